// Round 8
// baseline (51.606 us; speedup 1.0000x reference)
//
#include <hip/hip_runtime.h>
#include <hip/hip_bf16.h>

// out[n,f] = weights[n] * ( x[n,:] . Wsum[f,:] + bsum[f] )
// Wsum = sum_e W[e], bsum = sum_e b[e]  (expert sum commutes with Linear).
// Wsum stored fragment-major ("Bfrag") -> GEMM B-loads are lane-consecutive dense
// streams (R6-proven, -12.5us). R7: quarter-interleaved A staging (T14) + per-block
// K-rotation to spread HBM reads across the whole kernel lifetime, hw cvt_pk, NT stores.

#define N_TOK 32768
#define DIM   512
#define NEXP  8
#define BM    64            // tokens per block

typedef __attribute__((ext_vector_type(8))) short  bf16x8;
typedef __attribute__((ext_vector_type(4))) float  f32x4;

__device__ __forceinline__ unsigned int pk2bf(float a, float b) {
    unsigned ua = __float_as_uint(a), ub = __float_as_uint(b);
    ua = (ua + 0x7FFFu + ((ua >> 16) & 1u)) >> 16;   // RNE to bf16
    ub = (ub + 0x7FFFu + ((ub >> 16) & 1u)) >> 16;
    return ua | (ub << 16);
}

__device__ __forceinline__ unsigned int cvtpk(float a, float b) {
    unsigned r;
    asm("v_cvt_pk_bf16_f32 %0, %1, %2" : "=v"(r) : "v"(a), "v"(b));   // RNE, 1 instr
    return r;
}

// ---------------- prep: Bfrag (bf16, fragment-major) + bsum (f32) ---- (R6-proven) ----
__global__ __launch_bounds__(256) void moe_prep(const float* __restrict__ W,
                                                const float* __restrict__ b,
                                                unsigned short* __restrict__ Bfrag,
                                                float* __restrict__ bsum) {
    const int g = blockIdx.x * 256 + threadIdx.x;    // 0..32767
    const int f = g >> 6;
    const int q = g & 63;
    const float* src = W + (size_t)f * DIM + q * 8;
    float s0 = 0, s1 = 0, s2 = 0, s3 = 0, s4 = 0, s5 = 0, s6 = 0, s7 = 0;
#pragma unroll
    for (int e = 0; e < NEXP; ++e) {
        float4 u0 = *(const float4*)(src + (size_t)e * DIM * DIM);
        float4 u1 = *(const float4*)(src + (size_t)e * DIM * DIM + 4);
        s0 += u0.x; s1 += u0.y; s2 += u0.z; s3 += u0.w;
        s4 += u1.x; s5 += u1.y; s6 += u1.z; s7 += u1.w;
    }
    uint4 v;
    v.x = pk2bf(s0, s1); v.y = pk2bf(s2, s3);
    v.z = pk2bf(s4, s5); v.w = pk2bf(s6, s7);

    const int F  = f >> 6, j = (f >> 4) & 3, lr = f & 15;
    const int sl = q >> 2, lg = q & 3;
    const int idx16 = ((F * 4 + j) * 16 + sl) * 64 + (lg * 16 + lr);
    *(uint4*)(Bfrag + (size_t)idx16 * 8) = v;

    if (g < DIM / 4) {
        float4 bs = make_float4(0.f, 0.f, 0.f, 0.f);
#pragma unroll
        for (int e = 0; e < NEXP; ++e) {
            float4 u = *(const float4*)(b + e * DIM + g * 4);
            bs.x += u.x; bs.y += u.y; bs.z += u.z; bs.w += u.w;
        }
        *(float4*)(bsum + g * 4) = bs;
    }
}

// ---------------- main GEMM ----------------
// Block = 64 tokens x all 512 features; 8 waves, wave w owns features [w*64,(w+1)*64).
// K split into 4 quarters (128 k each). Block processes quarters in rotated order
// (rot = blockIdx&3) -- desyncs every block's HBM-read phase. Quarter q+1's global
// loads issue at chunk start (hidden under 4 MFMA slices), cvt_pk+ds_write at chunk
// end, one barrier per chunk. Each LDS quarter written exactly once -> no WAR.
// B: dense fragment-major streams (R6), depth-1 named-reg prefetch (bE/bO).
// Epilogue: swapped-operand direct dwordx4 NT stores (1.02x write amp, R3-proven).
__global__ __launch_bounds__(512, 2) void moe_gemm(const float* __restrict__ x,
                                                   const float* __restrict__ wts,
                                                   const unsigned short* __restrict__ Bf,
                                                   const float* __restrict__ bsum,
                                                   float* __restrict__ out) {
    __shared__ __align__(16) unsigned char ldsA[BM * DIM * 2];   // 64 KB

    const int tid  = threadIdx.x;
    const int lane = tid & 63;
    const int w    = tid >> 6;       // wave 0..7
    const int lr   = lane & 15;
    const int lg   = lane >> 4;
    const int m0   = blockIdx.x * BM;
    const int f0   = w * 64;
    const int rot  = blockIdx.x & 3;

    // A staging: thread -> row tid>>3 (0..63), k-granule slot as0 = tid&7.
    // Quarter q = granules q*16 + as0 + u*8, u in {0,1}; granule = 8 f32 -> 16B bf16.
    const int arow = tid >> 3;
    const int as0  = tid & 7;
    const float* asrc = x + (size_t)(m0 + arow) * DIM;
    unsigned char* arowp = ldsA + arow * 1024;

    auto loadQ = [&](int q, float4 (&r)[4]) {
        const float* p0 = asrc + (q * 16 + as0) * 8;
        const float* p1 = asrc + (q * 16 + as0 + 8) * 8;
        r[0] = *(const float4*)p0; r[1] = *(const float4*)(p0 + 4);
        r[2] = *(const float4*)p1; r[3] = *(const float4*)(p1 + 4);
    };
    auto writeQ = [&](int q, float4 (&r)[4]) {
#pragma unroll
        for (int u = 0; u < 2; ++u) {
            const int g  = q * 16 + as0 + u * 8;
            const int sg = (g & ~7) | ((g ^ arow) & 7);   // XOR swizzle (proven)
            uint4 v;
            v.x = cvtpk(r[2 * u].x,     r[2 * u].y);
            v.y = cvtpk(r[2 * u].z,     r[2 * u].w);
            v.z = cvtpk(r[2 * u + 1].x, r[2 * u + 1].y);
            v.w = cvtpk(r[2 * u + 1].z, r[2 * u + 1].w);
            *(uint4*)(arowp + sg * 16) = v;
        }
    };

    // B: dense fragment-major stream base (R6-proven)
    const bf16x8* bfr = (const bf16x8*)Bf + (size_t)w * 4096 + lane;   // + j*1024 + s*64

    f32x4 acc[4][4] = {};
    bf16x8 bE[4], bO[4], af[4];
    float4 st[4];

    auto loadB = [&](int s, bf16x8 (&bb)[4]) {
#pragma unroll
        for (int j = 0; j < 4; ++j)
            bb[j] = bfr[j * 1024 + s * 64];
    };
    auto sliceA = [&](int s) {
#pragma unroll
        for (int i = 0; i < 4; ++i) {
            const int row = i * 16 + lr;
            const int gsl = s * 4 + lg;
            const int sw  = (gsl & ~7) | ((gsl ^ row) & 7);
            af[i] = *(const bf16x8*)(ldsA + row * 1024 + sw * 16);
        }
    };
    auto mf = [&](bf16x8 (&bb)[4]) {
#pragma unroll
        for (int j = 0; j < 4; ++j)
#pragma unroll
            for (int i = 0; i < 4; ++i)
                acc[j][i] = __builtin_amdgcn_mfma_f32_16x16x32_bf16(bb[j], af[i], acc[j][i], 0, 0, 0);
    };

    // ---- prologue: stage quarter rot, prefetch first B slice
    loadQ(rot, st);
    writeQ(rot, st);            // dependency-waited on st's loads only
    loadB(rot * 4, bE);
    __syncthreads();

#pragma unroll
    for (int c = 0; c < 4; ++c) {
        const int q  = (rot + c) & 3;
        const int qn = (rot + c + 1) & 3;
        const int s0 = q * 4;
        if (c < 3) loadQ(qn, st);          // issue next quarter's HBM reads EARLY (T14)

#pragma unroll
        for (int t = 0; t < 4; t += 2) {
            loadB(s0 + t + 1, bO);                      // prefetch odd slice
            sliceA(s0 + t);
            mf(bE);
            const int snext = (t + 2 < 4) ? (s0 + t + 2) : (c < 3 ? qn * 4 : -1);
            if (snext >= 0) loadB(snext, bE);           // prefetch next even slice
            sliceA(s0 + t + 1);
            mf(bO);
        }

        if (c < 3) {
            writeQ(qn, st);                // convert + LDS write LATE
            __syncthreads();               // qn visible for next chunk
        }
    }

    // ---- epilogue: direct NT stores. token = m0 + i*16 + lr; feats = f0 + j*16 + lg*4
    f32x4 bs4[4];
#pragma unroll
    for (int j = 0; j < 4; ++j)
        bs4[j] = *(const f32x4*)(bsum + f0 + j * 16 + lg * 4);

#pragma unroll
    for (int i = 0; i < 4; ++i) {
        const int row = m0 + i * 16 + lr;
        const float wt = wts[row];
#pragma unroll
        for (int j = 0; j < 4; ++j) {
            f32x4 v;
            v[0] = wt * (acc[j][i][0] + bs4[j][0]);
            v[1] = wt * (acc[j][i][1] + bs4[j][1]);
            v[2] = wt * (acc[j][i][2] + bs4[j][2]);
            v[3] = wt * (acc[j][i][3] + bs4[j][3]);
            __builtin_nontemporal_store(v, (f32x4*)(out + (size_t)row * DIM + f0 + j * 16 + lg * 4));
        }
    }
}

extern "C" void kernel_launch(void* const* d_in, const int* in_sizes, int n_in,
                              void* d_out, int out_size, void* d_ws, size_t ws_size,
                              hipStream_t stream) {
    const float* x   = (const float*)d_in[0];   // [N, D]
    const float* wts = (const float*)d_in[1];   // [N, 1]
    const float* W   = (const float*)d_in[2];   // [E, D, D]
    const float* b   = (const float*)d_in[3];   // [E, D]
    float* out       = (float*)d_out;           // [N, D]

    unsigned short* Bfrag = (unsigned short*)d_ws;                    // 512 KB bf16
    float*          bsum  = (float*)((char*)d_ws + DIM * DIM * 2);    // 2 KB f32

    moe_prep<<<dim3((DIM * DIM / 8) / 256), dim3(256), 0, stream>>>(W, b, Bfrag, bsum);

    moe_gemm<<<dim3(N_TOK / BM), dim3(512), 0, stream>>>(x, wts, Bfrag, bsum, out);
}

// Round 9
// 44.698 us; speedup vs baseline: 1.1545x; 1.1545x over previous
//
#include <hip/hip_runtime.h>
#include <hip/hip_bf16.h>

// out[n,f] = weights[n] * ( x[n,:] . Wsum[f,:] + bsum[f] )
// Wsum = sum_e W[e], bsum = sum_e b[e]  (expert sum commutes with Linear).
// Wsum stored fragment-major ("Bfrag") -> GEMM B-loads are lane-consecutive dense
// streams (R6-proven, -12.5us). R8: BM=128 -- 32 MFMA per B-load-slice fully hides
// L2 latency under depth-1 prefetch; halves L2 B traffic. NT stores + rotation
// reverted (R7: +27MB write amplification, occupancy drop).

#define N_TOK 32768
#define DIM   512
#define NEXP  8
#define BM    128           // tokens per block

typedef __attribute__((ext_vector_type(8))) short  bf16x8;
typedef __attribute__((ext_vector_type(4))) float  f32x4;

__device__ __forceinline__ unsigned int pk2bf(float a, float b) {
    unsigned ua = __float_as_uint(a), ub = __float_as_uint(b);
    ua = (ua + 0x7FFFu + ((ua >> 16) & 1u)) >> 16;   // RNE to bf16
    ub = (ub + 0x7FFFu + ((ub >> 16) & 1u)) >> 16;
    return ua | (ub << 16);
}

// ---------------- prep: Bfrag (bf16, fragment-major) + bsum (f32) ---- (R6-proven) ----
__global__ __launch_bounds__(256) void moe_prep(const float* __restrict__ W,
                                                const float* __restrict__ b,
                                                unsigned short* __restrict__ Bfrag,
                                                float* __restrict__ bsum) {
    const int g = blockIdx.x * 256 + threadIdx.x;    // 0..32767
    const int f = g >> 6;
    const int q = g & 63;
    const float* src = W + (size_t)f * DIM + q * 8;
    float s0 = 0, s1 = 0, s2 = 0, s3 = 0, s4 = 0, s5 = 0, s6 = 0, s7 = 0;
#pragma unroll
    for (int e = 0; e < NEXP; ++e) {
        float4 u0 = *(const float4*)(src + (size_t)e * DIM * DIM);
        float4 u1 = *(const float4*)(src + (size_t)e * DIM * DIM + 4);
        s0 += u0.x; s1 += u0.y; s2 += u0.z; s3 += u0.w;
        s4 += u1.x; s5 += u1.y; s6 += u1.z; s7 += u1.w;
    }
    uint4 v;
    v.x = pk2bf(s0, s1); v.y = pk2bf(s2, s3);
    v.z = pk2bf(s4, s5); v.w = pk2bf(s6, s7);

    const int F  = f >> 6, j = (f >> 4) & 3, lr = f & 15;
    const int sl = q >> 2, lg = q & 3;
    const int idx16 = ((F * 4 + j) * 16 + sl) * 64 + (lg * 16 + lr);
    *(uint4*)(Bfrag + (size_t)idx16 * 8) = v;

    if (g < DIM / 4) {
        float4 bs = make_float4(0.f, 0.f, 0.f, 0.f);
#pragma unroll
        for (int e = 0; e < NEXP; ++e) {
            float4 u = *(const float4*)(b + e * DIM + g * 4);
            bs.x += u.x; bs.y += u.y; bs.z += u.z; bs.w += u.w;
        }
        *(float4*)(bsum + g * 4) = bs;
    }
}

// ---------------- main GEMM: stage-A-once + barrier-free K-loop + dense B ----------------
// Block = 128 tokens x all 512 features; 8 waves, wave w owns features [w*64,(w+1)*64).
// A (x, f32->bf16) staged ONCE into 128KB LDS (XOR-swizzled, R4-proven), 1 barrier.
// B: dense fragment-major streams from L2-resident Bfrag, depth-1 named-reg prefetch.
// Per slice: 4 B-loads feed 32 MFMAs (8 token frags) -> L2 latency fully hidden.
// MFMA operands swapped (mfma(B,A)): lane owns 4 consecutive features of one token
// -> direct dwordx4 stores (1.02x write amp, R6-proven).
__global__ __launch_bounds__(512, 2) void moe_gemm(const float* __restrict__ x,
                                                   const float* __restrict__ wts,
                                                   const unsigned short* __restrict__ Bf,
                                                   const float* __restrict__ bsum,
                                                   float* __restrict__ out) {
    __shared__ __align__(16) unsigned char ldsA[BM * DIM * 2];   // 128 KB

    const int tid  = threadIdx.x;
    const int lane = tid & 63;
    const int w    = tid >> 6;       // wave 0..7
    const int lr   = lane & 15;
    const int lg   = lane >> 4;
    const int m0   = blockIdx.x * BM;
    const int f0   = w * 64;

    // ---- stage A once: thread -> row tid>>2 (0..127), granule slot s0 = tid&3.
    //      Granules g = s0 + u*4 (u=0..15), each = 8 f32 -> 16B bf16, XOR-swizzled.
    {
        const int row = tid >> 2;
        const int s0  = tid & 3;
        const float* src = x + (size_t)(m0 + row) * DIM;
        unsigned char* dst = ldsA + row * 1024;
#pragma unroll
        for (int u = 0; u < 16; ++u) {
            const int g  = s0 + u * 4;
            float4 u0 = *(const float4*)(src + g * 8);
            float4 u1 = *(const float4*)(src + g * 8 + 4);
            const int sg = (g & ~7) | ((g ^ row) & 7);
            uint4 v;
            v.x = pk2bf(u0.x, u0.y); v.y = pk2bf(u0.z, u0.w);
            v.z = pk2bf(u1.x, u1.y); v.w = pk2bf(u1.z, u1.w);
            *(uint4*)(dst + sg * 16) = v;
        }
    }
    __syncthreads();   // the ONLY barrier

    // ---- dense B stream base: wave w's fragment block, this lane's 16B slot
    const bf16x8* bfr = (const bf16x8*)Bf + (size_t)w * 4096 + lane;   // + j*1024 + s*64

    f32x4 acc[4][8] = {};   // acc[j][i]: j = feature frag, i = token frag
    bf16x8 bE[4], bO[4], af[8];

    auto loadB = [&](int s, bf16x8 (&bb)[4]) {
#pragma unroll
        for (int j = 0; j < 4; ++j)
            bb[j] = bfr[j * 1024 + s * 64];
    };
    auto sliceA = [&](int s) {
#pragma unroll
        for (int i = 0; i < 8; ++i) {
            const int row = i * 16 + lr;
            const int gsl = s * 4 + lg;
            const int sw  = (gsl & ~7) | ((gsl ^ row) & 7);
            af[i] = *(const bf16x8*)(ldsA + row * 1024 + sw * 16);
        }
    };
    auto mf = [&](bf16x8 (&bb)[4]) {
#pragma unroll
        for (int j = 0; j < 4; ++j)
#pragma unroll
            for (int i = 0; i < 8; ++i)
                acc[j][i] = __builtin_amdgcn_mfma_f32_16x16x32_bf16(bb[j], af[i], acc[j][i], 0, 0, 0);
    };

    loadB(0, bE);
#pragma unroll
    for (int it = 0; it < 8; ++it) {
        loadB(2 * it + 1, bO);                      // prefetch odd slice
        sliceA(2 * it);
        mf(bE);
        if (it < 7) loadB(2 * it + 2, bE);          // prefetch even slice
        sliceA(2 * it + 1);
        mf(bO);
    }

    // ---- epilogue: direct stores. token = m0 + i*16 + lr; feats = f0 + j*16 + lg*4
    f32x4 bs4[4];
#pragma unroll
    for (int j = 0; j < 4; ++j)
        bs4[j] = *(const f32x4*)(bsum + f0 + j * 16 + lg * 4);

#pragma unroll
    for (int i = 0; i < 8; ++i) {
        const int row = m0 + i * 16 + lr;
        const float wt = wts[row];
#pragma unroll
        for (int j = 0; j < 4; ++j) {
            f32x4 v;
            v[0] = wt * (acc[j][i][0] + bs4[j][0]);
            v[1] = wt * (acc[j][i][1] + bs4[j][1]);
            v[2] = wt * (acc[j][i][2] + bs4[j][2]);
            v[3] = wt * (acc[j][i][3] + bs4[j][3]);
            *(f32x4*)(out + (size_t)row * DIM + f0 + j * 16 + lg * 4) = v;
        }
    }
}

extern "C" void kernel_launch(void* const* d_in, const int* in_sizes, int n_in,
                              void* d_out, int out_size, void* d_ws, size_t ws_size,
                              hipStream_t stream) {
    const float* x   = (const float*)d_in[0];   // [N, D]
    const float* wts = (const float*)d_in[1];   // [N, 1]
    const float* W   = (const float*)d_in[2];   // [E, D, D]
    const float* b   = (const float*)d_in[3];   // [E, D]
    float* out       = (float*)d_out;           // [N, D]

    unsigned short* Bfrag = (unsigned short*)d_ws;                    // 512 KB bf16
    float*          bsum  = (float*)((char*)d_ws + DIM * DIM * 2);    // 2 KB f32

    moe_prep<<<dim3((DIM * DIM / 8) / 256), dim3(256), 0, stream>>>(W, b, Bfrag, bsum);

    moe_gemm<<<dim3(N_TOK / BM), dim3(512), 0, stream>>>(x, wts, Bfrag, bsum, out);
}